// Round 1
// baseline (345.826 us; speedup 1.0000x reference)
//
#include <hip/hip_runtime.h>

// Fused: conv1d(64->64,k3,pad1)+relu -> conv1d(64->4,k3,pad1)+relu -> pixelshuffle(r=4)
// x: [32,64,16384] f32 ; out: [32, 65536] f32 with out[b, p*4+c] = h2[b,c,p]

#define CC 64
#define LL 16384
#define NB 32
#define TL 128

__global__ __launch_bounds__(256, 2)
void fused_upsample_f32(const float* __restrict__ x,
                        const float* __restrict__ w1,
                        const float* __restrict__ b1,
                        const float* __restrict__ w2,
                        const float* __restrict__ b2,
                        float* __restrict__ out) {
    // xs col c  <-> global pos t*TL - 2 + c   (c in 0..131)
    // hs col j  <-> global pos t*TL - 1 + j   (j in 0..129)
    __shared__ float xs[CC][134];
    __shared__ float hs[CC][132];

    const int t   = blockIdx.x;
    const int bb  = blockIdx.y;
    const int tid = threadIdx.x;

    // ---------------- stage x tile ----------------
    const int g0 = t * TL - 2;
    for (int i = tid; i < CC * 132; i += 256) {
        int ci  = i / 132;
        int col = i - ci * 132;
        int g   = g0 + col;
        float v = 0.f;
        if ((unsigned)g < (unsigned)LL)
            v = x[(bb * CC + ci) * LL + g];
        xs[ci][col] = v;
    }
    __syncthreads();

    // ---------------- conv1 + relu -> hs ----------------
    {
        const int co = tid >> 2;       // 0..63
        const int q  = tid & 3;        // 0..3
        const int p0 = q * 33;         // this thread's h-col range [p0, p0+33)
        const float bias = b1[co];
        float acc[33];
        #pragma unroll
        for (int i = 0; i < 33; ++i) acc[i] = bias;

        const float4* wp = (const float4*)(w1 + co * 192);
        #pragma unroll 1
        for (int c4 = 0; c4 < 16; ++c4) {
            float4 wa = wp[c4 * 3 + 0];
            float4 wb = wp[c4 * 3 + 1];
            float4 wc = wp[c4 * 3 + 2];
            float wk[4][3] = {{wa.x, wa.y, wa.z},
                              {wa.w, wb.x, wb.y},
                              {wb.z, wb.w, wc.x},
                              {wc.y, wc.z, wc.w}};
            #pragma unroll
            for (int u = 0; u < 4; ++u) {
                const int ci = c4 * 4 + u;
                float xv[35];
                #pragma unroll
                for (int i = 0; i < 35; ++i) xv[i] = xs[ci][p0 + i];
                #pragma unroll
                for (int i = 0; i < 33; ++i) {
                    acc[i] = fmaf(wk[u][0], xv[i],     acc[i]);
                    acc[i] = fmaf(wk[u][1], xv[i + 1], acc[i]);
                    acc[i] = fmaf(wk[u][2], xv[i + 2], acc[i]);
                }
            }
        }

        #pragma unroll
        for (int i = 0; i < 33; ++i) {
            int col = p0 + i;
            if (col < 130) {
                int gp = t * TL - 1 + col;     // global h position
                float v = fmaxf(acc[i], 0.f);
                if ((unsigned)gp >= (unsigned)LL) v = 0.f;  // conv2 zero-pads h
                hs[co][col] = v;
            }
        }
    }
    __syncthreads();

    // ---------------- conv2 + relu + pixelshuffle store ----------------
    {
        const int oc = tid & 3;        // 0..3
        const int j  = tid >> 2;       // 0..63  -> out cols j and j+64
        float a0 = b2[oc];
        float a1 = a0;
        const float4* wp = (const float4*)(w2 + oc * 192);
        #pragma unroll 1
        for (int c4 = 0; c4 < 16; ++c4) {
            float4 wa = wp[c4 * 3 + 0];
            float4 wb = wp[c4 * 3 + 1];
            float4 wc = wp[c4 * 3 + 2];
            float wk[4][3] = {{wa.x, wa.y, wa.z},
                              {wa.w, wb.x, wb.y},
                              {wb.z, wb.w, wc.x},
                              {wc.y, wc.z, wc.w}};
            #pragma unroll
            for (int u = 0; u < 4; ++u) {
                const int ci = c4 * 4 + u;
                float h0 = hs[ci][j];
                float h1 = hs[ci][j + 1];
                float h2 = hs[ci][j + 2];
                float g0v = hs[ci][j + 64];
                float g1v = hs[ci][j + 65];
                float g2v = hs[ci][j + 66];
                a0 = fmaf(wk[u][0], h0,  a0);
                a0 = fmaf(wk[u][1], h1,  a0);
                a0 = fmaf(wk[u][2], h2,  a0);
                a1 = fmaf(wk[u][0], g0v, a1);
                a1 = fmaf(wk[u][1], g1v, a1);
                a1 = fmaf(wk[u][2], g2v, a1);
            }
        }
        const int base = bb * (LL * 4) + (t * TL) * 4;
        out[base + j * 4 + oc]        = fmaxf(a0, 0.f);
        out[base + (j + 64) * 4 + oc] = fmaxf(a1, 0.f);
    }
}

extern "C" void kernel_launch(void* const* d_in, const int* in_sizes, int n_in,
                              void* d_out, int out_size, void* d_ws, size_t ws_size,
                              hipStream_t stream) {
    const float* x  = (const float*)d_in[0];
    const float* w1 = (const float*)d_in[1];
    const float* b1 = (const float*)d_in[2];
    const float* w2 = (const float*)d_in[3];
    const float* b2 = (const float*)d_in[4];
    float* out = (float*)d_out;

    dim3 grid(LL / TL, NB);
    fused_upsample_f32<<<grid, 256, 0, stream>>>(x, w1, b1, w2, b2, out);
}

// Round 3
// 64.110 us; speedup vs baseline: 5.3943x; 5.3943x over previous
//
#include <hip/hip_runtime.h>

// Fused bf16-MFMA: conv1d(64->64,k3,pad1)+relu -> conv1d(64->4,k3,pad1)+relu -> pixelshuffle(r=4)
// x: [32,64,16384] f32 ; out: [32, 65536] f32 with out[b, p*4+oc] = h2[b,oc,p]
//
// Conv as 3 tap-GEMMs: C[co][p] += W_k[co][ci] * x[ci][p+k-1], K=64 per tap (2 MFMA k-chunks).
// x staged transposed [pos][ci] bf16 in LDS, XOR-swizzled (byte ^= (row&7)<<4).
// h1 (bias+relu, zeroed outside [0,L)) stored back to LDS same layout for conv2.
// conv2 M=4 padded to 16 (zero weight rows); D lanes 0-15 hold float4 = out[p*4+0..3].
//
// R3 fix: conv1 — each wave owns co-tile `wave` and loops ALL 9 position tiles
// (R2 wrongly split position tiles across waves, leaving 3/4 of hs unwritten -> inf).

#define CC 64
#define LL 16384
#define NBATCH 32
#define TL 128
#define XROWS 146     // x pos range [t*TL-2, t*TL+143]
#define PITCH 128     // bytes per LDS row (64 bf16)

typedef short short8 __attribute__((ext_vector_type(8)));
typedef float f32x4 __attribute__((ext_vector_type(4)));

__device__ __forceinline__ unsigned short f2bf(float f) {
    unsigned u = __builtin_bit_cast(unsigned, f);
    u = (u + 0x7FFFu + ((u >> 16) & 1u)) >> 16;
    return (unsigned short)u;
}

// ---- weight repack: w1[64][64][3] f32 -> wp[k][co][ci] bf16 (12288)
//      w2[4][64][3]  f32 -> wp+12288 [k][oc16][ci] bf16 (3072), oc>=4 zero
__global__ void repack_weights(const float* __restrict__ w1,
                               const float* __restrict__ w2,
                               unsigned short* __restrict__ wp) {
    int i = blockIdx.x * 256 + threadIdx.x;
    if (i < 12288) {
        int kk = i >> 12;          // 0..2
        int rem = i & 4095;
        int co = rem >> 6;
        int ci = rem & 63;
        wp[i] = f2bf(w1[(co * 64 + ci) * 3 + kk]);
    }
    if (i < 3072) {
        int kk = i >> 10;
        int rem = i & 1023;
        int oc = rem >> 6;
        int ci = rem & 63;
        float v = (oc < 4) ? w2[(oc * 64 + ci) * 3 + kk] : 0.0f;
        wp[12288 + i] = f2bf(v);
    }
}

__global__ __launch_bounds__(256, 4)
void fused_upsample_mfma(const float* __restrict__ x,
                         const float* __restrict__ b1,
                         const float* __restrict__ b2,
                         const unsigned short* __restrict__ wp,
                         float* __restrict__ out) {
    __shared__ __align__(16) char lds[(148 + 144) * PITCH];
    char* const xs = lds;                      // rows 0..145 : x pos t*TL-2+row
    char* const hs = lds + 148 * PITCH;        // rows 0..143 : h pos t*TL-1+row

    const int t    = blockIdx.x;
    const int bb   = blockIdx.y;
    const int tid  = threadIdx.x;
    const int lane = tid & 63;
    const int wave = tid >> 6;
    const int lr   = lane & 15;   // fragment row/col index
    const int lg   = lane >> 4;   // k-chunk group 0..3

    // ---------------- stage x -> xs (transposed, bf16, swizzled) ----------------
    {
        const int c   = tid & 15;           // row within 16-chunk
        const int cg  = tid >> 4;           // ci-group 0..15
        const int ci0 = cg * 4;
        const long xbase = (long)(bb * CC + ci0) * LL;
        #pragma unroll
        for (int it = 0; it < 10; ++it) {
            int row = it * 16 + c;
            if (row < XROWS) {
                int gx = t * TL - 2 + row;
                bool ok = (unsigned)gx < (unsigned)LL;
                float v0 = ok ? x[xbase + gx]          : 0.f;
                float v1 = ok ? x[xbase + LL + gx]     : 0.f;
                float v2 = ok ? x[xbase + 2 * LL + gx] : 0.f;
                float v3 = ok ? x[xbase + 3 * LL + gx] : 0.f;
                unsigned lo = (unsigned)f2bf(v0) | ((unsigned)f2bf(v1) << 16);
                unsigned hi = (unsigned)f2bf(v2) | ((unsigned)f2bf(v3) << 16);
                int byte = (row * PITCH + ci0 * 2) ^ ((row & 7) << 4);
                *(uint2*)(xs + byte) = make_uint2(lo, hi);
            }
        }
    }
    __syncthreads();

    // ---------------- conv1: wave owns co-tile `wave`, loops all 9 pos-tiles ----------------
    {
        short8 A1[3][2];
        #pragma unroll
        for (int k = 0; k < 3; ++k)
            #pragma unroll
            for (int kc = 0; kc < 2; ++kc)
                A1[k][kc] = *(const short8*)(wp + ((k * 64 + wave * 16 + lr) * 64 + kc * 32 + lg * 8));

        const f32x4 bias1 = *(const f32x4*)(b1 + wave * 16 + lg * 4);

        #pragma unroll 1
        for (int i = 0; i < 9; ++i) {
            f32x4 acc = {0.f, 0.f, 0.f, 0.f};
            #pragma unroll
            for (int k = 0; k < 3; ++k) {
                int row = 16 * i + lr + k;             // xs row = p + k + 1
                #pragma unroll
                for (int kc = 0; kc < 2; ++kc) {
                    int byte = (row * PITCH + kc * 64 + lg * 16) ^ ((row & 7) << 4);
                    short8 Bf = *(const short8*)(xs + byte);
                    acc = __builtin_amdgcn_mfma_f32_16x16x32_bf16(A1[k][kc], Bf, acc, 0, 0, 0);
                }
            }
            // epilogue: bias + relu, zero outside global range, pack 4 bf16, write hs
            // D: col(p-offset)=lr, rows(co)=wave*16 + lg*4 + (0..3)
            int p  = 16 * i - 1 + lr;                  // local h pos
            int hp = t * TL + p;                       // global h pos
            bool inr = (unsigned)hp < (unsigned)LL;
            float r0 = inr ? fmaxf(acc[0] + bias1[0], 0.f) : 0.f;
            float r1 = inr ? fmaxf(acc[1] + bias1[1], 0.f) : 0.f;
            float r2 = inr ? fmaxf(acc[2] + bias1[2], 0.f) : 0.f;
            float r3 = inr ? fmaxf(acc[3] + bias1[3], 0.f) : 0.f;
            unsigned lo = (unsigned)f2bf(r0) | ((unsigned)f2bf(r1) << 16);
            unsigned hi = (unsigned)f2bf(r2) | ((unsigned)f2bf(r3) << 16);
            int hrow = 16 * i + lr;                    // hs row = p + 1
            int byte = (hrow * PITCH + wave * 32 + lg * 8) ^ ((hrow & 7) << 4);
            *(uint2*)(hs + byte) = make_uint2(lo, hi);
        }
    }
    __syncthreads();

    // ---------------- conv2 + pixelshuffle store: wave does 2 pos-tiles ----------------
    {
        short8 A2[3][2];
        #pragma unroll
        for (int k = 0; k < 3; ++k)
            #pragma unroll
            for (int kc = 0; kc < 2; ++kc)
                A2[k][kc] = *(const short8*)(wp + 12288 + ((k * 16 + lr) * 64 + kc * 32 + lg * 8));

        const f32x4 bias2 = *(const f32x4*)(b2);

        #pragma unroll
        for (int s = 0; s < 2; ++s) {
            int p0 = 16 * (wave * 2 + s);
            f32x4 acc = {0.f, 0.f, 0.f, 0.f};
            #pragma unroll
            for (int k = 0; k < 3; ++k) {
                int row = p0 + lr + k;                 // hs row = p + k
                #pragma unroll
                for (int kc = 0; kc < 2; ++kc) {
                    int byte = (row * PITCH + kc * 64 + lg * 16) ^ ((row & 7) << 4);
                    short8 Bf = *(const short8*)(hs + byte);
                    acc = __builtin_amdgcn_mfma_f32_16x16x32_bf16(A2[k][kc], Bf, acc, 0, 0, 0);
                }
            }
            if (lane < 16) {                           // lg=0: regs 0..3 = oc 0..3, col p = p0+lane
                f32x4 o;
                o[0] = fmaxf(acc[0] + bias2[0], 0.f);
                o[1] = fmaxf(acc[1] + bias2[1], 0.f);
                o[2] = fmaxf(acc[2] + bias2[2], 0.f);
                o[3] = fmaxf(acc[3] + bias2[3], 0.f);
                *(f32x4*)(out + (long)bb * (LL * 4) + (t * TL + p0 + lane) * 4) = o;
            }
        }
    }
}

extern "C" void kernel_launch(void* const* d_in, const int* in_sizes, int n_in,
                              void* d_out, int out_size, void* d_ws, size_t ws_size,
                              hipStream_t stream) {
    const float* x  = (const float*)d_in[0];
    const float* w1 = (const float*)d_in[1];
    const float* b1 = (const float*)d_in[2];
    const float* w2 = (const float*)d_in[3];
    const float* b2 = (const float*)d_in[4];
    float* out = (float*)d_out;
    unsigned short* wp = (unsigned short*)d_ws;

    repack_weights<<<48, 256, 0, stream>>>(w1, w2, wp);
    dim3 grid(LL / TL, NBATCH);
    fused_upsample_mfma<<<grid, 256, 0, stream>>>(x, b1, b2, wp, out);
}